// Round 1
// baseline (689.060 us; speedup 1.0000x reference)
//
#include <hip/hip_runtime.h>

typedef unsigned short u16;
typedef __attribute__((ext_vector_type(8))) short bf16x8;
typedef __attribute__((ext_vector_type(4))) float f32x4;
typedef __attribute__((ext_vector_type(4))) u16 u16x4;

#define C1 0.18033688011112042f   // log2(e)/8  (folds the 1/sqrt(64) score scale)

__device__ __forceinline__ u16 f2bf(float x){
  unsigned u = __float_as_uint(x);
  u += 0x7fffu + ((u >> 16) & 1u);
  return (u16)(u >> 16);
}
__device__ __forceinline__ float bf2f(u16 h){ return __uint_as_float(((unsigned)h) << 16); }
__device__ __forceinline__ void fsplit(float x, u16 &h, u16 &l){
  h = f2bf(x);
  l = f2bf(x - bf2f(h));
}

// Stage a [ROWS][64]-bf16 tile (row = 128B) into LDS with XOR-swizzled 16B slots.
// Read back with frag(): both sides use slot ^ (row&7)  -> 2-way-max bank aliasing.
template<int ROWS, int NT>
__device__ __forceinline__ void stage_tile(bf16x8* lds, const u16* __restrict__ g,
                                           size_t row0, int ldg, int col0, int tid){
#pragma unroll
  for (int p = 0; p < (ROWS*8)/NT; ++p){
    int idx = tid + p*NT;
    int r = idx >> 3, slot = idx & 7;
    bf16x8 v = *(const bf16x8*)(g + (row0 + (size_t)r)*(size_t)ldg + col0 + slot*8);
    lds[r*8 + (slot ^ (r & 7))] = v;
  }
}

__device__ __forceinline__ bf16x8 frag(const bf16x8* lds, int r, int slot){
  return lds[r*8 + (slot ^ (r & 7))];
}

// split-bf16 3-term product: X*Y ~= Xh*Yh + Xh*Yl + Xl*Yh   (fp32 accumulate)
__device__ __forceinline__ f32x4 mfma3(bf16x8 xh, bf16x8 xl, bf16x8 yh, bf16x8 yl, f32x4 c){
  c = __builtin_amdgcn_mfma_f32_16x16x32_bf16(xh, yh, c, 0, 0, 0);
  c = __builtin_amdgcn_mfma_f32_16x16x32_bf16(xh, yl, c, 0, 0, 0);
  c = __builtin_amdgcn_mfma_f32_16x16x32_bf16(xl, yh, c, 0, 0, 0);
  return c;
}

// ---------------- elementwise split: fp32 -> (hi,lo) bf16 ----------------
__global__ void __launch_bounds__(256) k_split_in(const float* __restrict__ x,
                                                  u16* __restrict__ hh, u16* __restrict__ ll, int n4){
  for (int i = blockIdx.x*256 + threadIdx.x; i < n4; i += gridDim.x*256){
    float4 v = ((const float4*)x)[i];
    float a[4] = {v.x, v.y, v.z, v.w};
    u16x4 h, l;
#pragma unroll
    for (int j = 0; j < 4; ++j){ u16 p, q; fsplit(a[j], p, q); h[j] = p; l[j] = q; }
    *(u16x4*)(hh + (size_t)i*4) = h;
    *(u16x4*)(ll + (size_t)i*4) = l;
  }
}

// ---------------- weight transpose + split: W[k][n] -> Wt[n][k] hi/lo ----------------
__global__ void __launch_bounds__(256) k_wsplit(const float* __restrict__ W,
                                                u16* __restrict__ Th, u16* __restrict__ Tl){
  __shared__ float t[32][33];
  int tx = threadIdx.x & 31, ty = threadIdx.x >> 5;      // 32 x 8
  int n0 = blockIdx.x*32, k0 = blockIdx.y*32;
#pragma unroll
  for (int i = 0; i < 4; ++i)
    t[ty + 8*i][tx] = W[(size_t)(k0 + ty + 8*i)*1024 + n0 + tx];
  __syncthreads();
#pragma unroll
  for (int i = 0; i < 4; ++i){
    int n = n0 + ty + 8*i, k = k0 + tx;
    u16 a, b; fsplit(t[tx][ty + 8*i], a, b);
    Th[(size_t)n*1024 + k] = a;
    Tl[(size_t)n*1024 + k] = b;
  }
}

// ---------------- projection / output GEMM ----------------
// C(4096x1024) = A(4096x1024) * Bt^T (+bias), tile 128x64, 4 waves x (32 rows x 64 cols)
// MODE 0: Q  -> LN, natural head-major split write
// MODE 1: K  -> LN, natural + transposed split writes
// MODE 2: V  -> transposed split write
// MODE 3: out-> fp32 write to d_out
template<int MODE>
__global__ void __launch_bounds__(256, 3) k_proj(
    const u16* __restrict__ Ah, const u16* __restrict__ Al,
    const u16* __restrict__ Bh, const u16* __restrict__ Bl,
    const float* __restrict__ bias, const float* __restrict__ gamma, const float* __restrict__ beta,
    u16* __restrict__ Nh, u16* __restrict__ Nl,
    u16* __restrict__ Th, u16* __restrict__ Tl,
    float* __restrict__ Fo)
{
  __shared__ bf16x8 sAh[128*8], sAl[128*8], sBh[64*8], sBl[64*8];
  const int tid = threadIdx.x, lane = tid & 63, w = tid >> 6;
  const int cl = lane & 15, gq = lane >> 4;
  const int nt = blockIdx.x, mt = blockIdx.y;
  f32x4 acc[2][4] = {};
  for (int kt = 0; kt < 16; ++kt){
    __syncthreads();
    stage_tile<128,256>(sAh, Ah, (size_t)mt*128, 1024, kt*64, tid);
    stage_tile<128,256>(sAl, Al, (size_t)mt*128, 1024, kt*64, tid);
    stage_tile<64,256>(sBh, Bh, (size_t)nt*64, 1024, kt*64, tid);
    stage_tile<64,256>(sBl, Bl, (size_t)nt*64, 1024, kt*64, tid);
    __syncthreads();
#pragma unroll
    for (int ks = 0; ks < 2; ++ks){
      const int slot = ks*4 + gq;
      bf16x8 ah0 = frag(sAh, w*32 + cl, slot);
      bf16x8 al0 = frag(sAl, w*32 + cl, slot);
      bf16x8 ah1 = frag(sAh, w*32 + 16 + cl, slot);
      bf16x8 al1 = frag(sAl, w*32 + 16 + cl, slot);
#pragma unroll
      for (int f = 0; f < 4; ++f){
        bf16x8 bh_ = frag(sBh, f*16 + cl, slot);
        bf16x8 bl_ = frag(sBl, f*16 + cl, slot);
        acc[0][f] = mfma3(ah0, al0, bh_, bl_, acc[0][f]);
        acc[1][f] = mfma3(ah1, al1, bh_, bl_, acc[1][f]);
      }
    }
  }
  float bv[4];
#pragma unroll
  for (int f = 0; f < 4; ++f) bv[f] = bias[nt*64 + f*16 + cl];
  float gm[4], bt[4];
  if constexpr (MODE <= 1){
#pragma unroll
    for (int f = 0; f < 4; ++f){ gm[f] = gamma[f*16 + cl]; bt[f] = beta[f*16 + cl]; }
  }
#pragma unroll
  for (int mi = 0; mi < 2; ++mi){
    float v[4][4];
#pragma unroll
    for (int f = 0; f < 4; ++f)
#pragma unroll
      for (int r = 0; r < 4; ++r) v[f][r] = acc[mi][f][r] + bv[f];
    if constexpr (MODE <= 1){
#pragma unroll
      for (int r = 0; r < 4; ++r){
        float s1 = v[0][r] + v[1][r] + v[2][r] + v[3][r];
        float s2 = v[0][r]*v[0][r] + v[1][r]*v[1][r] + v[2][r]*v[2][r] + v[3][r]*v[3][r];
#pragma unroll
        for (int d = 1; d < 16; d <<= 1){ s1 += __shfl_xor(s1, d); s2 += __shfl_xor(s2, d); }
        float mu = s1 * (1.f/64.f);
        float var = s2 * (1.f/64.f) - mu*mu;
        float rs = rsqrtf(var + 1e-5f);
#pragma unroll
        for (int f = 0; f < 4; ++f) v[f][r] = (v[f][r] - mu)*rs*gm[f] + bt[f];
      }
    }
    const int mrow = mt*128 + w*32 + mi*16 + gq*4;   // + r
    if constexpr (MODE == 3){
#pragma unroll
      for (int f = 0; f < 4; ++f)
#pragma unroll
        for (int r = 0; r < 4; ++r)
          Fo[(size_t)(mrow + r)*1024 + nt*64 + f*16 + cl] = v[f][r];
    } else {
      const int b = mrow >> 11, srow = mrow & 2047;
      const size_t hb = (size_t)(b*16 + nt);          // head-major (b*16 + head)
      if constexpr (MODE <= 1){
#pragma unroll
        for (int f = 0; f < 4; ++f)
#pragma unroll
          for (int r = 0; r < 4; ++r){
            u16 h_, l_; fsplit(v[f][r], h_, l_);
            size_t ix = (hb*2048 + srow + r)*64 + f*16 + cl;
            Nh[ix] = h_; Nl[ix] = l_;
          }
      }
      if constexpr (MODE == 1 || MODE == 2){
#pragma unroll
        for (int f = 0; f < 4; ++f){
          u16x4 h4, l4;
#pragma unroll
          for (int r = 0; r < 4; ++r){ u16 a_, b_; fsplit(v[f][r], a_, b_); h4[r] = a_; l4[r] = b_; }
          size_t ix = (hb*64 + f*16 + cl)*2048 + srow;
          *(u16x4*)(Th + ix) = h4;
          *(u16x4*)(Tl + ix) = l4;
        }
      }
    }
  }
}

// ---------------- Hopfield flash-attention step ----------------
// 8 waves x 16 q-rows (QB=128), KB=64. Swapped operands: St = K*Q^T so softmax
// stats are lane-local per q (col = lane&15). O^T = V^T * P^T.
// FINAL=0: q_new = softmax(q k^T/8) k, written in place (block owns its q rows).
// FINAL=1: out   = softmax(q k^T/8) v, split-written to (row, h*64+d).
template<int FINAL>
__global__ void __launch_bounds__(512, 4) k_attn(
    u16* __restrict__ Qh, u16* __restrict__ Ql,
    const u16* __restrict__ Kh, const u16* __restrict__ Kl,
    const u16* __restrict__ Th, const u16* __restrict__ Tl,   // Kt (update) or Vt (final)
    u16* __restrict__ Oh, u16* __restrict__ Ol)
{
  __shared__ bf16x8 sKh[64*8], sKl[64*8], sVh[64*8], sVl[64*8];
  __shared__ bf16x8 sP[8][2][176];                 // per-wave P: 16 rows x 176B stride (pad)
  const int tid = threadIdx.x, lane = tid & 63, w = tid >> 6;
  const int cl = lane & 15, gq = lane >> 4;
  int flat = blockIdx.x;
  flat = (flat & 7)*64 + (flat >> 3);              // XCD swizzle: 4 consecutive bh per XCD
  const int bh = flat >> 4, qt = flat & 15;
  const size_t base = (size_t)bh * (2048*64);
  const int q = qt*128 + w*16 + cl;

  bf16x8 qfh[2], qfl[2];
#pragma unroll
  for (int ks = 0; ks < 2; ++ks){
    size_t ix = base + (size_t)q*64 + ks*32 + gq*8;
    qfh[ks] = *(const bf16x8*)(Qh + ix);
    qfl[ks] = *(const bf16x8*)(Ql + ix);
  }
  float m_run = -1e30f, l_run = 0.f;
  f32x4 accO[4] = {};
  char* pbh = (char*)&sP[w][0][0];
  char* pbl = (char*)&sP[w][1][0];

  for (int kt = 0; kt < 32; ++kt){
    __syncthreads();
    stage_tile<64,512>(sKh, Kh, (size_t)bh*2048 + kt*64, 64, 0, tid);
    stage_tile<64,512>(sKl, Kl, (size_t)bh*2048 + kt*64, 64, 0, tid);
    stage_tile<64,512>(sVh, Th, (size_t)bh*64, 2048, kt*64, tid);
    stage_tile<64,512>(sVl, Tl, (size_t)bh*64, 2048, kt*64, tid);
    __syncthreads();

    f32x4 S[4] = {};
#pragma unroll
    for (int ks = 0; ks < 2; ++ks){
      const int slot = ks*4 + gq;
#pragma unroll
      for (int i = 0; i < 4; ++i){
        bf16x8 kh_ = frag(sKh, i*16 + cl, slot);
        bf16x8 kl_ = frag(sKl, i*16 + cl, slot);
        S[i] = mfma3(kh_, kl_, qfh[ks], qfl[ks], S[i]);   // St[kv][q]
      }
    }
    // online softmax over kv for this thread's q-column (cl); kv spread over gq groups
    float tmax = -1e30f;
#pragma unroll
    for (int i = 0; i < 4; ++i)
#pragma unroll
      for (int r = 0; r < 4; ++r) tmax = fmaxf(tmax, S[i][r]);
    tmax = fmaxf(tmax, __shfl_xor(tmax, 16));
    tmax = fmaxf(tmax, __shfl_xor(tmax, 32));
    const float m_new = fmaxf(m_run, tmax);
    const float alpha = exp2f((m_run - m_new)*C1);
    float ts = 0.f;
#pragma unroll
    for (int i = 0; i < 4; ++i){
      u16x4 h4, l4;
#pragma unroll
      for (int r = 0; r < 4; ++r){
        float p = exp2f((S[i][r] - m_new)*C1);
        ts += p;
        u16 a_, b_; fsplit(p, a_, b_); h4[r] = a_; l4[r] = b_;
      }
      const int off = cl*176 + (i*16 + gq*4)*2;    // P[q=cl][kv], kv-contiguous
      *(u16x4*)(pbh + off) = h4;
      *(u16x4*)(pbl + off) = l4;
    }
    ts += __shfl_xor(ts, 16);
    ts += __shfl_xor(ts, 32);
    l_run = l_run*alpha + ts;
    m_run = m_new;
#pragma unroll
    for (int db = 0; db < 4; ++db) accO[db] *= alpha;
    // O^T += V^T * P^T  (per-wave P, no barrier needed: wave-local LDS ordering)
#pragma unroll
    for (int ks = 0; ks < 2; ++ks){
      const int slot = ks*4 + gq;
      bf16x8 ph = *(const bf16x8*)(pbh + cl*176 + ks*64 + gq*16);
      bf16x8 pl = *(const bf16x8*)(pbl + cl*176 + ks*64 + gq*16);
#pragma unroll
      for (int db = 0; db < 4; ++db){
        bf16x8 vh_ = frag(sVh, db*16 + cl, slot);
        bf16x8 vl_ = frag(sVl, db*16 + cl, slot);
        accO[db] = mfma3(vh_, vl_, ph, pl, accO[db]);
      }
    }
  }
  const float inv = 1.f / l_run;
  if constexpr (FINAL){
    const int b = bh >> 4, h = bh & 15;
    const size_t row = (size_t)b*2048 + q;
#pragma unroll
    for (int db = 0; db < 4; ++db){
      u16x4 h4, l4;
#pragma unroll
      for (int r = 0; r < 4; ++r){ u16 a_, b_; fsplit(accO[db][r]*inv, a_, b_); h4[r] = a_; l4[r] = b_; }
      size_t ix = row*1024 + h*64 + db*16 + gq*4;
      *(u16x4*)(Oh + ix) = h4;
      *(u16x4*)(Ol + ix) = l4;
    }
  } else {
#pragma unroll
    for (int db = 0; db < 4; ++db){
      u16x4 h4, l4;
#pragma unroll
      for (int r = 0; r < 4; ++r){ u16 a_, b_; fsplit(accO[db][r]*inv, a_, b_); h4[r] = a_; l4[r] = b_; }
      size_t ix = base + (size_t)q*64 + db*16 + gq*4;
      *(u16x4*)(Qh + ix) = h4;
      *(u16x4*)(Ql + ix) = l4;
    }
  }
}

extern "C" void kernel_launch(void* const* d_in, const int* in_sizes, int n_in,
                              void* d_out, int out_size, void* d_ws, size_t ws_size,
                              hipStream_t stream) {
  (void)in_sizes; (void)n_in; (void)out_size; (void)ws_size;
  const float* query = (const float*)d_in[0];
  const float* key   = (const float*)d_in[1];
  const float* value = (const float*)d_in[2];
  const float* Wq = (const float*)d_in[3];
  const float* bq = (const float*)d_in[4];
  const float* Wk = (const float*)d_in[5];
  const float* bk = (const float*)d_in[6];
  const float* Wv = (const float*)d_in[7];
  const float* bv = (const float*)d_in[8];
  const float* Wo = (const float*)d_in[9];
  const float* bo = (const float*)d_in[10];
  const float* gamma = (const float*)d_in[11];
  const float* beta  = (const float*)d_in[12];
  float* out = (float*)d_out;

  char* ws = (char*)d_ws;
  const size_t MB = 1024*1024;
  u16* inq_h = (u16*)(ws + 0*MB),  *inq_l = (u16*)(ws + 8*MB);
  u16* ink_h = (u16*)(ws + 16*MB), *ink_l = (u16*)(ws + 24*MB);
  u16* inv_h = (u16*)(ws + 32*MB), *inv_l = (u16*)(ws + 40*MB);
  u16* wq_h = (u16*)(ws + 48*MB), *wq_l = (u16*)(ws + 50*MB);
  u16* wk_h = (u16*)(ws + 52*MB), *wk_l = (u16*)(ws + 54*MB);
  u16* wv_h = (u16*)(ws + 56*MB), *wv_l = (u16*)(ws + 58*MB);
  u16* wo_h = (u16*)(ws + 60*MB), *wo_l = (u16*)(ws + 62*MB);
  u16* Qh  = (u16*)(ws + 64*MB),  *Ql  = (u16*)(ws + 72*MB);
  u16* Kh  = (u16*)(ws + 80*MB),  *Kl  = (u16*)(ws + 88*MB);
  u16* Kth = (u16*)(ws + 96*MB),  *Ktl = (u16*)(ws + 104*MB);
  u16* Vth = (u16*)(ws + 112*MB), *Vtl = (u16*)(ws + 120*MB);
  u16* Oh = inq_h, *Ol = inq_l;    // reuse: inq dead after proj<0>

  const int n4 = 4096*1024/4;
  k_split_in<<<dim3(2048), dim3(256), 0, stream>>>(query, inq_h, inq_l, n4);
  k_split_in<<<dim3(2048), dim3(256), 0, stream>>>(key,   ink_h, ink_l, n4);
  k_split_in<<<dim3(2048), dim3(256), 0, stream>>>(value, inv_h, inv_l, n4);
  k_wsplit<<<dim3(32,32), dim3(256), 0, stream>>>(Wq, wq_h, wq_l);
  k_wsplit<<<dim3(32,32), dim3(256), 0, stream>>>(Wk, wk_h, wk_l);
  k_wsplit<<<dim3(32,32), dim3(256), 0, stream>>>(Wv, wv_h, wv_l);
  k_wsplit<<<dim3(32,32), dim3(256), 0, stream>>>(Wo, wo_h, wo_l);

  k_proj<0><<<dim3(16,32), dim3(256), 0, stream>>>(inq_h, inq_l, wq_h, wq_l, bq, gamma, beta,
                                                   Qh, Ql, nullptr, nullptr, nullptr);
  k_proj<1><<<dim3(16,32), dim3(256), 0, stream>>>(ink_h, ink_l, wk_h, wk_l, bk, gamma, beta,
                                                   Kh, Kl, Kth, Ktl, nullptr);
  k_proj<2><<<dim3(16,32), dim3(256), 0, stream>>>(inv_h, inv_l, wv_h, wv_l, bv, nullptr, nullptr,
                                                   nullptr, nullptr, Vth, Vtl, nullptr);

  for (int it = 0; it < 3; ++it)
    k_attn<0><<<dim3(512), dim3(512), 0, stream>>>(Qh, Ql, Kh, Kl, Kth, Ktl, nullptr, nullptr);
  k_attn<1><<<dim3(512), dim3(512), 0, stream>>>(Qh, Ql, Kh, Kl, Vth, Vtl, Oh, Ol);

  k_proj<3><<<dim3(16,32), dim3(256), 0, stream>>>(Oh, Ol, wo_h, wo_l, bo, nullptr, nullptr,
                                                   nullptr, nullptr, nullptr, nullptr, out);
}